// Round 5
// baseline (319.085 us; speedup 1.0000x reference)
//
#include <hip/hip_runtime.h>
#include <math.h>

// SparseGate: B=16384, D=2048, E=64, k=2
#define NROWS 16384
#define DDIM  2048
#define NEXP  64
#define NCOL  128            // fused: 64 gate cols + 64 noise cols

constexpr float TAU = 1e-3f;        // margin below which we recheck in fp32

typedef __attribute__((ext_vector_type(8))) short short8;
typedef __attribute__((ext_vector_type(4))) float floatx4;

// ---------------- fp32 -> bf16 hi/lo truncation split ----------------
__device__ __forceinline__ void split8(const float4 a, const float4 b,
                                       short8* hi, short8* lo)
{
    float f[8] = {a.x, a.y, a.z, a.w, b.x, b.y, b.z, b.w};
    union { unsigned short u[8]; short8 v; } H, L;
    #pragma unroll
    for (int j = 0; j < 8; ++j) {
        const unsigned int u  = __float_as_uint(f[j]);
        const unsigned int hf = u & 0xFFFF0000u;
        const float lf = f[j] - __uint_as_float(hf);   // exact
        H.u[j] = (unsigned short)(u >> 16);
        L.u[j] = (unsigned short)(__float_as_uint(lf) >> 16);
    }
    *hi = H.v; *lo = L.v;
}

__device__ __forceinline__ float softplus_f(float x) {
    return fmaxf(x, 0.f) + log1pf(expf(-fabsf(x)));
}

// ---------------- top-k + softmax over a 64-lane row ----------------
__device__ __forceinline__ float row_gate(int lane, float ew, int k, float* margin)
{
    float cur = ew;
    const float myv = ew;
    float m0 = 0.f, denom = 0.f, vk = 0.f, vk1 = 0.f;
    int selected = 0;
    const int iters = (k < NEXP) ? (k + 1) : k;
    for (int t = 0; t < iters; ++t) {
        float v = cur;
        int idx = lane;
        #pragma unroll
        for (int off = 32; off; off >>= 1) {
            const float ov = __shfl_xor(v, off);
            const int   oi = __shfl_xor(idx, off);
            if (ov > v || (ov == v && oi < idx)) { v = ov; idx = oi; }
        }
        if (t == 0) m0 = v;
        if (t < k) {
            denom += expf(v - m0);
            vk = v;
            if (lane == idx) { selected = 1; cur = -INFINITY; }
        } else {
            vk1 = v;
        }
    }
    *margin = (k < NEXP) ? (vk - vk1) : 1e30f;
    return selected ? expf(myv - m0) / denom : 0.f;
}

// ---------------- weight prep: fp32 -> bf16 hi/lo in MFMA fragment order ----
// whilo (shorts): [((col*64 + kt)*4 + quad) * 16] = hi8 | lo8. Total 1 MB.
__global__ __launch_bounds__(256) void wprep_kernel(
    const float* __restrict__ gw, const float* __restrict__ nw,
    unsigned short* __restrict__ whilo, int* __restrict__ counter)
{
    const int g = blockIdx.x * 256 + threadIdx.x;    // 0..32767
    if (g == 0) counter[0] = 0;
    const int col  = g >> 8;                          // 0..127
    const int kt   = (g >> 2) & 63;
    const int quad = g & 3;
    const float* src = (col < NEXP) ? (gw + (size_t)col * DDIM)
                                    : (nw + (size_t)(col - NEXP) * DDIM);
    src += kt * 32 + quad * 8;
    const float4 a = *(const float4*)src;
    const float4 b = *(const float4*)(src + 4);
    short8 hi, lo;
    split8(a, b, &hi, &lo);
    unsigned short* dst = whilo + (size_t)g * 16;
    *(short8*)dst       = hi;
    *(short8*)(dst + 8) = lo;
}

// ---------------- split-K GEMM: partials only, no LDS, no barriers ----------
// Block = 64 rows x 64 cols x (DDIM/S) k. 4 waves = 2 row-halves x 2 col-halves.
// Wave = 32 rows x 32 cols (rt=2, ct=2), 12 MFMA / 32-k step.
// Grid = 256 rowTiles x 2 colTiles x S. part[split][row][col] fp32.
__global__ __launch_bounds__(256, 4) void gemm_kernel(
    const float* __restrict__ x,
    const unsigned short* __restrict__ whilo,
    float* __restrict__ part,
    int S)
{
    const int tid    = threadIdx.x;
    const int wv     = tid >> 6;
    const int ln     = tid & 63;
    const int lane15 = ln & 15;
    const int quad   = ln >> 4;

    const int bid     = blockIdx.x;
    const int rowTile = bid / (2 * S);     // same-x blocks adjacent -> L3 reuse
    const int rem     = bid % (2 * S);
    const int colTile = rem / S;
    const int split   = rem % S;

    const int kps = DDIM / S;              // k per split
    const int kit = kps >> 5;              // 32-k iterations (>=16)
    const int k0  = split * kps;
    const int kt0 = k0 >> 5;

    const int rowbase = rowTile * 64 + (wv >> 1) * 32;
    const int colbase = colTile * 64 + (wv & 1) * 32;

    // A: row = rowbase + rt*16 + lane15, k = k0 + kt*32 + quad*8
    const float* xp0 = x + (size_t)(rowbase + lane15) * DDIM + k0 + quad * 8;
    const float* xp1 = xp0 + (size_t)16 * DDIM;
    // B: col = colbase + ct*16 + lane15; shorts idx = col*4096 + kt*64 + quad*16
    const unsigned short* bp0 = whilo + (size_t)(colbase + lane15) * 4096
                                      + (size_t)kt0 * 64 + quad * 16;
    const unsigned short* bp1 = bp0 + (size_t)16 * 4096;

    floatx4 acc[2][2];
    #pragma unroll
    for (int rt = 0; rt < 2; ++rt)
        #pragma unroll
        for (int ct = 0; ct < 2; ++ct)
            acc[rt][ct] = (floatx4){0.f, 0.f, 0.f, 0.f};

    float4 a0[2][2], a1[2][2];    // [rt][half] — depth-2 A pipeline
    short8 bcur[2][2];            // [ct][hi/lo] — depth-1 B

    a0[0][0] = *(const float4*)(xp0 + 0);
    a0[0][1] = *(const float4*)(xp0 + 4);
    a0[1][0] = *(const float4*)(xp1 + 0);
    a0[1][1] = *(const float4*)(xp1 + 4);
    a1[0][0] = *(const float4*)(xp0 + 32);
    a1[0][1] = *(const float4*)(xp0 + 36);
    a1[1][0] = *(const float4*)(xp1 + 32);
    a1[1][1] = *(const float4*)(xp1 + 36);
    bcur[0][0] = *(const short8*)(bp0 + 0);
    bcur[0][1] = *(const short8*)(bp0 + 8);
    bcur[1][0] = *(const short8*)(bp1 + 0);
    bcur[1][1] = *(const short8*)(bp1 + 8);

    for (int kt = 0; kt < kit; ++kt) {
        short8 ahi[2], alo[2];
        split8(a0[0][0], a0[0][1], &ahi[0], &alo[0]);
        split8(a0[1][0], a0[1][1], &ahi[1], &alo[1]);
        short8 bh[2] = {bcur[0][0], bcur[1][0]};
        short8 bl[2] = {bcur[0][1], bcur[1][1]};

        // Issue B (L2-hit, needed next iter) BEFORE A so the B-wait next
        // iteration does not drain the deeper A queue (vmcnt is in-order).
        if (kt + 1 < kit) {
            const int o = (kt + 1) * 64;
            bcur[0][0] = *(const short8*)(bp0 + o);
            bcur[0][1] = *(const short8*)(bp0 + o + 8);
            bcur[1][0] = *(const short8*)(bp1 + o);
            bcur[1][1] = *(const short8*)(bp1 + o + 8);
        }
        #pragma unroll
        for (int rt = 0; rt < 2; ++rt)
            #pragma unroll
            for (int h = 0; h < 2; ++h)
                a0[rt][h] = a1[rt][h];
        if (kt + 2 < kit) {
            const int o = (kt + 2) * 32;
            a1[0][0] = *(const float4*)(xp0 + o);
            a1[0][1] = *(const float4*)(xp0 + o + 4);
            a1[1][0] = *(const float4*)(xp1 + o);
            a1[1][1] = *(const float4*)(xp1 + o + 4);
        }

        #pragma unroll
        for (int rt = 0; rt < 2; ++rt)
            #pragma unroll
            for (int ct = 0; ct < 2; ++ct) {
                acc[rt][ct] = __builtin_amdgcn_mfma_f32_16x16x32_bf16(ahi[rt], bh[ct], acc[rt][ct], 0, 0, 0);
                acc[rt][ct] = __builtin_amdgcn_mfma_f32_16x16x32_bf16(ahi[rt], bl[ct], acc[rt][ct], 0, 0, 0);
                acc[rt][ct] = __builtin_amdgcn_mfma_f32_16x16x32_bf16(alo[rt], bh[ct], acc[rt][ct], 0, 0, 0);
            }
    }

    // store partials (C/D layout: col=lane15, row=quad*4+reg)
    float* pp = part + (size_t)split * NROWS * NCOL;
    #pragma unroll
    for (int rt = 0; rt < 2; ++rt)
        #pragma unroll
        for (int r = 0; r < 4; ++r) {
            const int row = rowbase + rt * 16 + quad * 4 + r;
            float* rowp = pp + (size_t)row * NCOL + colbase + lane15;
            rowp[0]  = acc[rt][0][r];
            rowp[16] = acc[rt][1][r];
        }
}

// ---------------- combine + gate: sum splits, softplus/noise, top-k --------
__global__ __launch_bounds__(256) void combine_kernel(
    const float* __restrict__ part,
    const float* __restrict__ noise,
    const int* __restrict__ kptr,
    float* __restrict__ out,
    int* __restrict__ counter,
    int* __restrict__ list,
    int S)
{
    const int ln  = threadIdx.x & 63;
    const int row = blockIdx.x * 4 + (threadIdx.x >> 6);
    if (row >= NROWS) return;

    int k = kptr[0];
    if (k < 1) k = 1;
    if (k > NEXP) k = NEXP;

    float clean = 0.f, noisy = 0.f;
    for (int s = 0; s < S; ++s) {
        const float* p = part + ((size_t)s * NROWS + row) * NCOL;
        clean += p[ln];
        noisy += p[NEXP + ln];
    }
    const float nz = noise[(size_t)row * NEXP + ln];
    const float ew = clean + nz * softplus_f(noisy);
    float margin;
    const float val = row_gate(ln, ew, k, &margin);
    out[(size_t)row * NEXP + ln] = val;
    if (margin < TAU && ln == 0) {
        const int pos = atomicAdd(counter, 1);
        list[pos] = row;
    }
}

// ---------------- exact fp32 recheck for low-margin rows ----------------
__global__ __launch_bounds__(256) void recheck_kernel(
    const float* __restrict__ x,
    const float* __restrict__ gw,
    const float* __restrict__ nw,
    const float* __restrict__ noise,
    const int* __restrict__ kptr,
    float* __restrict__ out,
    const int* __restrict__ counter,
    const int* __restrict__ list)
{
    __shared__ float xr[DDIM];      // 8 KB
    __shared__ float parts[256];
    __shared__ float lg[NCOL];

    const int tid = threadIdx.x;
    const int cnt = counter[0];

    int k = kptr[0];
    if (k < 1) k = 1;
    if (k > NEXP) k = NEXP;

    for (int ii = blockIdx.x; ii < cnt; ii += gridDim.x) {
        const int row = list[ii];
        const float4* xs = (const float4*)(x + (size_t)row * DDIM);
        #pragma unroll
        for (int j = 0; j < 2; ++j)
            ((float4*)xr)[tid + j * 256] = xs[tid + j * 256];
        __syncthreads();

        const int e = tid & 127;
        const int half = tid >> 7;
        const float* wc = (e < NEXP) ? (gw + (size_t)e * DDIM)
                                     : (nw + (size_t)(e - NEXP) * DDIM);
        wc += half * 1024;
        const float* xc = xr + half * 1024;
        float s = 0.f;
        #pragma unroll 4
        for (int j = 0; j < 1024; j += 4) {
            float4 w4 = *(const float4*)&wc[j];
            s += xc[j] * w4.x + xc[j + 1] * w4.y + xc[j + 2] * w4.z + xc[j + 3] * w4.w;
        }
        parts[tid] = s;
        __syncthreads();
        if (tid < NCOL) lg[tid] = parts[tid] + parts[tid + 128];
        __syncthreads();
        if (tid < NEXP) {
            const float ew = lg[tid] + noise[(size_t)row * NEXP + tid] * softplus_f(lg[NEXP + tid]);
            float margin;
            const float val = row_gate(tid, ew, k, &margin);
            out[(size_t)row * NEXP + tid] = val;
        }
        __syncthreads();
    }
}

// ---------------- fallback: exact per-row (only if ws too small) ----------------
__global__ __launch_bounds__(256) void naive_kernel(
    const float* __restrict__ x,
    const float* __restrict__ gw,
    const float* __restrict__ nw,
    const float* __restrict__ noise,
    const int* __restrict__ kptr,
    float* __restrict__ out)
{
    const int lane = threadIdx.x & 63;
    const int wave = threadIdx.x >> 6;
    const int row  = blockIdx.x * 4 + wave;
    if (row >= NROWS) return;

    int k = kptr[0];
    if (k < 1) k = 1;
    if (k > NEXP) k = NEXP;

    const float* xr = x  + (size_t)row  * DDIM;
    const float* g  = gw + (size_t)lane * DDIM;
    const float* w2 = nw + (size_t)lane * DDIM;
    float c = 0.f, n = 0.f;
    for (int d = 0; d < DDIM; ++d) {
        const float xv = xr[d];
        c += xv * g[d];
        n += xv * w2[d];
    }
    const float ew = c + noise[(size_t)row * NEXP + lane] * softplus_f(n);
    float margin;
    out[(size_t)row * NEXP + lane] = row_gate(lane, ew, k, &margin);
}

// ---------------------------------------------------------------------------
extern "C" void kernel_launch(void* const* d_in, const int* in_sizes, int n_in,
                              void* d_out, int out_size, void* d_ws, size_t ws_size,
                              hipStream_t stream)
{
    const float* x     = (const float*)d_in[0];
    const float* gw    = (const float*)d_in[1];
    const float* nw    = (const float*)d_in[2];
    const float* noise = (const float*)d_in[3];
    const int*   kptr  = (const int*)d_in[4];
    float* out = (float*)d_out;

    // ws: part (S*8 MB) | whilo (1 MB) | counter (256 B) | list (64 KB)
    const size_t PART_SPLIT  = (size_t)NROWS * NCOL * sizeof(float);           // 8 MB
    const size_t WHILO_BYTES = (size_t)NCOL * DDIM * 2 * sizeof(unsigned short); // 1 MB
    const size_t TAIL        = 256 + NROWS * sizeof(int);

    int S = 0;
    if      (ws_size >= 4 * PART_SPLIT + WHILO_BYTES + TAIL) S = 4;
    else if (ws_size >= 2 * PART_SPLIT + WHILO_BYTES + TAIL) S = 2;
    else if (ws_size >= 1 * PART_SPLIT + WHILO_BYTES + TAIL) S = 1;

    if (S == 0) {
        hipLaunchKernelGGL(naive_kernel, dim3(NROWS / 4), dim3(256), 0, stream,
                           x, gw, nw, noise, kptr, out);
        return;
    }

    float*          part    = (float*)d_ws;
    unsigned short* whilo   = (unsigned short*)((char*)d_ws + (size_t)S * PART_SPLIT);
    int*            counter = (int*)((char*)whilo + WHILO_BYTES);
    int*            list    = counter + 64;

    hipLaunchKernelGGL(wprep_kernel, dim3(128), dim3(256), 0, stream,
                       gw, nw, whilo, counter);
    hipLaunchKernelGGL(gemm_kernel, dim3(256 * 2 * S), dim3(256), 0, stream,
                       x, whilo, part, S);
    hipLaunchKernelGGL(combine_kernel, dim3(NROWS / 4), dim3(256), 0, stream,
                       part, noise, kptr, out, counter, list, S);
    hipLaunchKernelGGL(recheck_kernel, dim3(256), dim3(256), 0, stream,
                       x, gw, nw, noise, kptr, out, counter, list);
}

// Round 6
// 260.680 us; speedup vs baseline: 1.2240x; 1.2240x over previous
//
#include <hip/hip_runtime.h>
#include <math.h>

// SparseGate: B=16384, D=2048, E=64, k=2
#define NROWS 16384
#define DDIM  2048
#define NEXP  64
#define NCOL  128            // fused: 64 gate cols + 64 noise cols

constexpr float TAU = 1e-3f;        // margin below which we recheck in fp32

typedef __attribute__((ext_vector_type(8))) short short8;
typedef __attribute__((ext_vector_type(4))) float floatx4;

// ---------------- fp32 -> bf16 hi/lo truncation split ----------------
__device__ __forceinline__ void split8(const float4 a, const float4 b,
                                       short8* hi, short8* lo)
{
    float f[8] = {a.x, a.y, a.z, a.w, b.x, b.y, b.z, b.w};
    union { unsigned short u[8]; short8 v; } H, L;
    #pragma unroll
    for (int j = 0; j < 8; ++j) {
        const unsigned int u  = __float_as_uint(f[j]);
        const unsigned int hf = u & 0xFFFF0000u;
        const float lf = f[j] - __uint_as_float(hf);   // exact
        H.u[j] = (unsigned short)(u >> 16);
        L.u[j] = (unsigned short)(__float_as_uint(lf) >> 16);
    }
    *hi = H.v; *lo = L.v;
}

__device__ __forceinline__ float softplus_f(float x) {
    return fmaxf(x, 0.f) + log1pf(expf(-fabsf(x)));
}

// ---------------- top-k + softmax over a 64-lane row ----------------
__device__ __forceinline__ float row_gate(int lane, float ew, int k, float* margin)
{
    float cur = ew;
    const float myv = ew;
    float m0 = 0.f, denom = 0.f, vk = 0.f, vk1 = 0.f;
    int selected = 0;
    const int iters = (k < NEXP) ? (k + 1) : k;
    for (int t = 0; t < iters; ++t) {
        float v = cur;
        int idx = lane;
        #pragma unroll
        for (int off = 32; off; off >>= 1) {
            const float ov = __shfl_xor(v, off);
            const int   oi = __shfl_xor(idx, off);
            if (ov > v || (ov == v && oi < idx)) { v = ov; idx = oi; }
        }
        if (t == 0) m0 = v;
        if (t < k) {
            denom += expf(v - m0);
            vk = v;
            if (lane == idx) { selected = 1; cur = -INFINITY; }
        } else {
            vk1 = v;
        }
    }
    *margin = (k < NEXP) ? (vk - vk1) : 1e30f;
    return selected ? expf(myv - m0) / denom : 0.f;
}

// ---------------- weight prep: pack B in exact wave-read order ----------------
// Bpk short index: (((kt*8 + ct)*2 + h)*64 + ln)*8 + j   (1 MB total)
// value = bf16 part h of W[col = ct*16 + (ln&15)][k = kt*32 + (ln>>4)*8 + j]
// -> at fragment time, a wave reading (kt, ct, h) loads lane ln -> base + ln*16B:
//    perfectly coalesced 1 KB per instruction.
__global__ __launch_bounds__(256) void wprep_kernel(
    const float* __restrict__ gw, const float* __restrict__ nw,
    unsigned short* __restrict__ bpk, int* __restrict__ counter)
{
    const int g = blockIdx.x * 256 + threadIdx.x;    // 0..32767
    if (g == 0) counter[0] = 0;
    const int kt = g >> 9;            // 0..63
    const int ct = (g >> 6) & 7;      // 0..7
    const int ln = g & 63;            // 0..63
    const int col = ct * 16 + (ln & 15);
    const int kb  = kt * 32 + (ln >> 4) * 8;
    const float* src = (col < NEXP) ? (gw + (size_t)col * DDIM)
                                    : (nw + (size_t)(col - NEXP) * DDIM);
    src += kb;
    const float4 a = *(const float4*)src;
    const float4 b = *(const float4*)(src + 4);
    short8 hi, lo;
    split8(a, b, &hi, &lo);
    const size_t base = ((size_t)(kt * 8 + ct) * 2) * 512 + (size_t)ln * 8;
    *(short8*)&bpk[base]       = hi;    // h=0
    *(short8*)&bpk[base + 512] = lo;    // h=1
}

// ---------------- split-K GEMM, m97-style A staging ----------------
// Block = 64 rows x 128 cols x (DDIM/S) k; 256 threads = 4 waves (2 row x 2 col).
// Wave = 32 rows x 64 cols: rt=2, ct=4, 24 MFMA per 32-k iter.
// A: global fp32 -> regs -> split8 -> LDS bf16 (double-buffered, 1 barrier/iter).
// B: direct coalesced global fragment loads from bpk (L2-hot), depth-1 prefetch.
__global__ __launch_bounds__(256, 4) void gemm_kernel(
    const float* __restrict__ x,
    const unsigned short* __restrict__ bpk,
    float* __restrict__ part,
    int S)
{
    // [buf][quad][h][row][8 shorts] = 16 KB; fragment read: 16 consecutive
    // lanes (lane15) -> 16 consecutive 16B chunks -> floor-rate ds_read_b128.
    __shared__ __align__(16) unsigned short ldsA[2][4][2][64][8];

    const int tid  = threadIdx.x;
    const int wv   = tid >> 6;
    const int ln   = tid & 63;
    const int l15  = ln & 15;
    const int quad = ln >> 4;

    const int rowTile = blockIdx.x & 255;        // grid.x = 256*S
    const int split   = blockIdx.x >> 8;
    const int kps = DDIM / S;
    const int kit = kps >> 5;
    const int k0  = split * kps;
    const int kt0 = k0 >> 5;

    const int rowbase = rowTile * 64;

    // staging assignment: thread t -> row st_r = t>>2 (64 rows), quad st_q = t&3
    const int st_r = tid >> 2;
    const int st_q = tid & 3;
    const float* xs = x + (size_t)(rowbase + st_r) * DDIM + k0 + st_q * 8;

    // wave tile
    const int rh     = (wv >> 1) * 32;           // row half
    const int ctbase = (wv & 1) * 4;             // col quarter base (4 ct's)

    const short8* bp = (const short8*)bpk;       // idx = ((kt*8+ct)*2+h)*64 + ln

    floatx4 acc[2][4];
    #pragma unroll
    for (int rt = 0; rt < 2; ++rt)
        #pragma unroll
        for (int ct = 0; ct < 4; ++ct)
            acc[rt][ct] = (floatx4){0.f, 0.f, 0.f, 0.f};

    // preamble: A(0) regs, B(0) regs
    float4 ar0 = *(const float4*)(xs);
    float4 ar1 = *(const float4*)(xs + 4);
    short8 bcur[4][2];
    #pragma unroll
    for (int ct = 0; ct < 4; ++ct) {
        bcur[ct][0] = bp[(size_t)((kt0 * 8 + ctbase + ct) * 2 + 0) * 64 + ln];
        bcur[ct][1] = bp[(size_t)((kt0 * 8 + ctbase + ct) * 2 + 1) * 64 + ln];
    }

    for (int kt = 0; kt < kit; ++kt) {
        const int buf = kt & 1;
        // ---- stage A(kt): consume regs (vmcnt wait), convert, LDS write ----
        {
            short8 hi, lo;
            split8(ar0, ar1, &hi, &lo);
            *(short8*)&ldsA[buf][st_q][0][st_r][0] = hi;
            *(short8*)&ldsA[buf][st_q][1][st_r][0] = lo;
        }
        __syncthreads();   // staging visible; double-buffer isolates readers

        // ---- issue A(kt+1) now (post-barrier: flies during MFMA phase) ----
        if (kt + 1 < kit) {
            const float* xn = xs + (kt + 1) * 32;
            ar0 = *(const float4*)(xn);
            ar1 = *(const float4*)(xn + 4);
        }

        // ---- A fragments from LDS ----
        short8 ahi[2], alo[2];
        #pragma unroll
        for (int rt = 0; rt < 2; ++rt) {
            const int row = rh + rt * 16 + l15;
            ahi[rt] = *(const short8*)&ldsA[buf][quad][0][row][0];
            alo[rt] = *(const short8*)&ldsA[buf][quad][1][row][0];
        }

        // ---- MFMA: consume bcur, prefetch B(kt+1) per-ct ----
        const int ktg = kt0 + kt;
        #pragma unroll
        for (int ct = 0; ct < 4; ++ct) {
            const short8 bh = bcur[ct][0];
            const short8 bl = bcur[ct][1];
            if (kt + 1 < kit) {
                bcur[ct][0] = bp[(size_t)(((ktg + 1) * 8 + ctbase + ct) * 2 + 0) * 64 + ln];
                bcur[ct][1] = bp[(size_t)(((ktg + 1) * 8 + ctbase + ct) * 2 + 1) * 64 + ln];
            }
            acc[0][ct] = __builtin_amdgcn_mfma_f32_16x16x32_bf16(ahi[0], bh, acc[0][ct], 0, 0, 0);
            acc[1][ct] = __builtin_amdgcn_mfma_f32_16x16x32_bf16(ahi[1], bh, acc[1][ct], 0, 0, 0);
            acc[0][ct] = __builtin_amdgcn_mfma_f32_16x16x32_bf16(ahi[0], bl, acc[0][ct], 0, 0, 0);
            acc[1][ct] = __builtin_amdgcn_mfma_f32_16x16x32_bf16(ahi[1], bl, acc[1][ct], 0, 0, 0);
            acc[0][ct] = __builtin_amdgcn_mfma_f32_16x16x32_bf16(alo[0], bh, acc[0][ct], 0, 0, 0);
            acc[1][ct] = __builtin_amdgcn_mfma_f32_16x16x32_bf16(alo[1], bh, acc[1][ct], 0, 0, 0);
        }
    }

    // ---- store partials (C/D: col=lane15, row=quad*4+reg) ----
    float* pp = part + (size_t)split * NROWS * NCOL;
    #pragma unroll
    for (int rt = 0; rt < 2; ++rt)
        #pragma unroll
        for (int r = 0; r < 4; ++r) {
            const int row = rowbase + rh + rt * 16 + quad * 4 + r;
            float* rowp = pp + (size_t)row * NCOL + (wv & 1) * 64 + l15;
            #pragma unroll
            for (int ct = 0; ct < 4; ++ct)
                rowp[ct * 16] = acc[rt][ct][r];
        }
}

// ---------------- combine + gate: sum splits, softplus/noise, top-k --------
__global__ __launch_bounds__(256) void combine_kernel(
    const float* __restrict__ part,
    const float* __restrict__ noise,
    const int* __restrict__ kptr,
    float* __restrict__ out,
    int* __restrict__ counter,
    int* __restrict__ list,
    int S)
{
    const int ln  = threadIdx.x & 63;
    const int row = blockIdx.x * 4 + (threadIdx.x >> 6);
    if (row >= NROWS) return;

    int k = kptr[0];
    if (k < 1) k = 1;
    if (k > NEXP) k = NEXP;

    float clean = 0.f, noisy = 0.f;
    for (int s = 0; s < S; ++s) {
        const float* p = part + ((size_t)s * NROWS + row) * NCOL;
        clean += p[ln];
        noisy += p[NEXP + ln];
    }
    const float nz = noise[(size_t)row * NEXP + ln];
    const float ew = clean + nz * softplus_f(noisy);
    float margin;
    const float val = row_gate(ln, ew, k, &margin);
    out[(size_t)row * NEXP + ln] = val;
    if (margin < TAU && ln == 0) {
        const int pos = atomicAdd(counter, 1);
        list[pos] = row;
    }
}

// ---------------- exact fp32 recheck for low-margin rows ----------------
__global__ __launch_bounds__(256) void recheck_kernel(
    const float* __restrict__ x,
    const float* __restrict__ gw,
    const float* __restrict__ nw,
    const float* __restrict__ noise,
    const int* __restrict__ kptr,
    float* __restrict__ out,
    const int* __restrict__ counter,
    const int* __restrict__ list)
{
    __shared__ float xr[DDIM];      // 8 KB
    __shared__ float parts[256];
    __shared__ float lg[NCOL];

    const int tid = threadIdx.x;
    const int cnt = counter[0];

    int k = kptr[0];
    if (k < 1) k = 1;
    if (k > NEXP) k = NEXP;

    for (int ii = blockIdx.x; ii < cnt; ii += gridDim.x) {
        const int row = list[ii];
        const float4* xs = (const float4*)(x + (size_t)row * DDIM);
        #pragma unroll
        for (int j = 0; j < 2; ++j)
            ((float4*)xr)[tid + j * 256] = xs[tid + j * 256];
        __syncthreads();

        const int e = tid & 127;
        const int half = tid >> 7;
        const float* wc = (e < NEXP) ? (gw + (size_t)e * DDIM)
                                     : (nw + (size_t)(e - NEXP) * DDIM);
        wc += half * 1024;
        const float* xc = xr + half * 1024;
        float s = 0.f;
        #pragma unroll 4
        for (int j = 0; j < 1024; j += 4) {
            float4 w4 = *(const float4*)&wc[j];
            s += xc[j] * w4.x + xc[j + 1] * w4.y + xc[j + 2] * w4.z + xc[j + 3] * w4.w;
        }
        parts[tid] = s;
        __syncthreads();
        if (tid < NCOL) lg[tid] = parts[tid] + parts[tid + 128];
        __syncthreads();
        if (tid < NEXP) {
            const float ew = lg[tid] + noise[(size_t)row * NEXP + tid] * softplus_f(lg[NEXP + tid]);
            float margin;
            const float val = row_gate(tid, ew, k, &margin);
            out[(size_t)row * NEXP + tid] = val;
        }
        __syncthreads();
    }
}

// ---------------- fallback: exact per-row (only if ws too small) ----------------
__global__ __launch_bounds__(256) void naive_kernel(
    const float* __restrict__ x,
    const float* __restrict__ gw,
    const float* __restrict__ nw,
    const float* __restrict__ noise,
    const int* __restrict__ kptr,
    float* __restrict__ out)
{
    const int lane = threadIdx.x & 63;
    const int wave = threadIdx.x >> 6;
    const int row  = blockIdx.x * 4 + wave;
    if (row >= NROWS) return;

    int k = kptr[0];
    if (k < 1) k = 1;
    if (k > NEXP) k = NEXP;

    const float* xr = x  + (size_t)row  * DDIM;
    const float* g  = gw + (size_t)lane * DDIM;
    const float* w2 = nw + (size_t)lane * DDIM;
    float c = 0.f, n = 0.f;
    for (int d = 0; d < DDIM; ++d) {
        const float xv = xr[d];
        c += xv * g[d];
        n += xv * w2[d];
    }
    const float ew = c + noise[(size_t)row * NEXP + lane] * softplus_f(n);
    float margin;
    out[(size_t)row * NEXP + lane] = row_gate(lane, ew, k, &margin);
}

// ---------------------------------------------------------------------------
extern "C" void kernel_launch(void* const* d_in, const int* in_sizes, int n_in,
                              void* d_out, int out_size, void* d_ws, size_t ws_size,
                              hipStream_t stream)
{
    const float* x     = (const float*)d_in[0];
    const float* gw    = (const float*)d_in[1];
    const float* nw    = (const float*)d_in[2];
    const float* noise = (const float*)d_in[3];
    const int*   kptr  = (const int*)d_in[4];
    float* out = (float*)d_out;

    // ws: part (S*8 MB) | bpk (1 MB) | counter (256 B) | list (64 KB)
    const size_t PART_SPLIT = (size_t)NROWS * NCOL * sizeof(float);             // 8 MB
    const size_t BPK_BYTES  = (size_t)NCOL * DDIM * 2 * sizeof(unsigned short); // 1 MB
    const size_t TAIL       = 256 + NROWS * sizeof(int);

    int S = 0;
    if      (ws_size >= 4 * PART_SPLIT + BPK_BYTES + TAIL) S = 4;
    else if (ws_size >= 2 * PART_SPLIT + BPK_BYTES + TAIL) S = 2;
    else if (ws_size >= 1 * PART_SPLIT + BPK_BYTES + TAIL) S = 1;

    if (S == 0) {
        hipLaunchKernelGGL(naive_kernel, dim3(NROWS / 4), dim3(256), 0, stream,
                           x, gw, nw, noise, kptr, out);
        return;
    }

    float*          part    = (float*)d_ws;
    unsigned short* bpk     = (unsigned short*)((char*)d_ws + (size_t)S * PART_SPLIT);
    int*            counter = (int*)((char*)bpk + BPK_BYTES);
    int*            list    = counter + 64;

    hipLaunchKernelGGL(wprep_kernel, dim3(128), dim3(256), 0, stream,
                       gw, nw, bpk, counter);
    hipLaunchKernelGGL(gemm_kernel, dim3(256 * S), dim3(256), 0, stream,
                       x, bpk, part, S);
    hipLaunchKernelGGL(combine_kernel, dim3(NROWS / 4), dim3(256), 0, stream,
                       part, noise, kptr, out, counter, list, S);
    hipLaunchKernelGGL(recheck_kernel, dim3(256), dim3(256), 0, stream,
                       x, gw, nw, noise, kptr, out, counter, list);
}